// Round 1
// baseline (279.387 us; speedup 1.0000x reference)
//
#include <hip/hip_runtime.h>

// ---- types ----
typedef _Float16 half8 __attribute__((ext_vector_type(8)));
typedef _Float16 half4v __attribute__((ext_vector_type(4)));
typedef float f4 __attribute__((ext_vector_type(4)));

#define ASYNC_COPY16(ldsp, gp)                                                     \
  __builtin_amdgcn_global_load_lds((__attribute__((address_space(1))) void*)(gp),  \
                                   (__attribute__((address_space(3))) void*)(ldsp),\
                                   16, 0, 0)

__device__ __forceinline__ f4 mfma16(half8 a, half8 b, f4 c) {
  return __builtin_amdgcn_mfma_f32_16x16x32_f16(a, b, c, 0, 0, 0);
}

// Problem constants
// B=2 S=2048 E=1024 H=16 D=64, M = B*S = 4096

// ---- 1. fp32 -> fp16 cast of x ----
__global__ __launch_bounds__(256) void k_cvt_x(const float* __restrict__ x,
                                               _Float16* __restrict__ xh) {
  int i = (blockIdx.x * 256 + threadIdx.x) * 4;
  f4 v = *(const f4*)(x + i);
  half4v h;
  h[0] = (_Float16)v[0]; h[1] = (_Float16)v[1];
  h[2] = (_Float16)v[2]; h[3] = (_Float16)v[3];
  *(half4v*)(xh + i) = h;
}

// ---- 2. W [K=1024][N=1024] fp32 -> Wt [N][K] fp16 (LDS tiled transpose) ----
__global__ __launch_bounds__(256) void k_transpose_w(const float* __restrict__ w,
                                                     _Float16* __restrict__ wt) {
  __shared__ float tw[32][33];
  int k0 = blockIdx.y * 32, n0 = blockIdx.x * 32;
  int tx = threadIdx.x, ty = threadIdx.y;
  for (int j = 0; j < 32; j += 8) tw[ty + j][tx] = w[(size_t)(k0 + ty + j) * 1024 + n0 + tx];
  __syncthreads();
  for (int j = 0; j < 32; j += 8)
    wt[(size_t)(n0 + ty + j) * 1024 + k0 + tx] = (_Float16)tw[tx][ty + j];
}

// ---- 3. fused QKV projection GEMM ----
// A [4096][1024] fp16, Bt [3072][1024] fp16 (Wq^T|Wk^T|Wv^T). Out: Q/K/V fp16 [B,H,S,D].
__global__ __launch_bounds__(256) void k_gemm_proj(
    const _Float16* __restrict__ A, const _Float16* __restrict__ Bt,
    const float* __restrict__ bq, const float* __restrict__ bk, const float* __restrict__ bv,
    _Float16* __restrict__ Qo, _Float16* __restrict__ Ko, _Float16* __restrict__ Vo) {
  __shared__ __align__(16) _Float16 As[128 * 32];
  __shared__ __align__(16) _Float16 Bs[128 * 32];
  const int t = threadIdx.x, lane = t & 63, w = t >> 6;
  const int qd = lane >> 4, lr = lane & 15;
  const int m0 = blockIdx.y * 128, n0 = blockIdx.x * 128;
  const int wm = (w & 1) * 64, wn = (w >> 1) * 64;
  const f4 z4 = {0.f, 0.f, 0.f, 0.f};
  f4 acc[4][4];
#pragma unroll
  for (int i = 0; i < 4; ++i)
#pragma unroll
    for (int j = 0; j < 4; ++j) acc[i][j] = z4;

  const int c0 = t, c1 = t + 256;
  for (int k0 = 0; k0 < 1024; k0 += 32) {
    const _Float16* ga0 = A + (size_t)(m0 + (c0 >> 2)) * 1024 + k0 + (c0 & 3) * 8;
    const _Float16* ga1 = A + (size_t)(m0 + (c1 >> 2)) * 1024 + k0 + (c1 & 3) * 8;
    const _Float16* gb0 = Bt + (size_t)(n0 + (c0 >> 2)) * 1024 + k0 + (c0 & 3) * 8;
    const _Float16* gb1 = Bt + (size_t)(n0 + (c1 >> 2)) * 1024 + k0 + (c1 & 3) * 8;
    char* la = (char*)As + w * 1024;
    char* lb = (char*)Bs + w * 1024;
    ASYNC_COPY16(la, ga0);
    ASYNC_COPY16(la + 4096, ga1);
    ASYNC_COPY16(lb, gb0);
    ASYNC_COPY16(lb + 4096, gb1);
    __syncthreads();
    half8 af[4], bf[4];
#pragma unroll
    for (int i = 0; i < 4; ++i)
      af[i] = *(const half8*)(As + (wm + i * 16 + lr) * 32 + qd * 8);
#pragma unroll
    for (int j = 0; j < 4; ++j)
      bf[j] = *(const half8*)(Bs + (wn + j * 16 + lr) * 32 + qd * 8);
#pragma unroll
    for (int i = 0; i < 4; ++i)
#pragma unroll
      for (int j = 0; j < 4; ++j) acc[i][j] = mfma16(af[i], bf[j], acc[i][j]);
    __syncthreads();
  }

  const int mat = n0 >> 10;
  const float* bias = (mat == 0) ? bq : (mat == 1) ? bk : bv;
  _Float16* outp = (mat == 0) ? Qo : (mat == 1) ? Ko : Vo;
#pragma unroll
  for (int i = 0; i < 4; ++i)
#pragma unroll
    for (int j = 0; j < 4; ++j)
#pragma unroll
      for (int r = 0; r < 4; ++r) {
        int m = m0 + wm + i * 16 + qd * 4 + r;
        int n = (n0 + wn + j * 16 + lr) & 1023;
        float v = acc[i][j][r] + bias[n];
        int bb = m >> 11, s = m & 2047, hh = n >> 6, d = n & 63;
        outp[(size_t)((bb * 16 + hh) * 2048 + s) * 64 + d] = (_Float16)v;
      }
}

// ---- 4. V [B,H,S,D] -> Vt [B,H,D,S] ----
__global__ __launch_bounds__(256) void k_transpose_v(const _Float16* __restrict__ V,
                                                     _Float16* __restrict__ Vt) {
  __shared__ __align__(16) _Float16 tv[64][72];
  int bh = blockIdx.y, s0 = blockIdx.x * 64;
  int t = threadIdx.x;
  const _Float16* vb = V + (size_t)(bh * 2048 + s0) * 64;
  for (int j = 0; j < 2; ++j) {
    int c = t + j * 256;
    int row = c >> 3, off = (c & 7) * 8;
    *(f4*)&tv[row][off] = *(const f4*)(vb + row * 64 + off);
  }
  __syncthreads();
  _Float16* ob = Vt + (size_t)bh * 64 * 2048 + s0;
  for (int j = 0; j < 2; ++j) {
    int c = t + j * 256;
    int d = c >> 3, so = (c & 7) * 8;
    half8 h;
#pragma unroll
    for (int u = 0; u < 8; ++u) h[u] = tv[so + u][d];
    *(half8*)(ob + (size_t)d * 2048 + so) = h;
  }
}

// ---- 5. flash attention ----
// Q [B,H,S,D], K [B,H,S,D], Vt [B,H,D,S] fp16; mask [B,S] int32; ctx out fp16 [B*S][E]
__global__ __launch_bounds__(256) void k_attn(
    const _Float16* __restrict__ Qg, const _Float16* __restrict__ Kg,
    const _Float16* __restrict__ Vtg, const int* __restrict__ maskg,
    _Float16* __restrict__ ctx) {
  __shared__ __align__(16) _Float16 Qs[128][72];
  __shared__ __align__(16) _Float16 Ks[64][72];
  __shared__ __align__(16) _Float16 Vts[64][72];
  __shared__ __align__(16) _Float16 Ps[4][32][72];
  __shared__ float Msk[64];

  const int bh = blockIdx.y;
  const int b = bh >> 4, h = bh & 15;
  const int q0 = blockIdx.x * 128;
  const int t = threadIdx.x, lane = t & 63, w = t >> 6;
  const int qd = lane >> 4, lr = lane & 15;

  {
    const _Float16* Qb = Qg + (size_t)(bh * 2048 + q0) * 64;
    for (int j = 0; j < 4; ++j) {
      int c = t + j * 256;
      int row = c >> 3, off = (c & 7) * 8;
      *(f4*)&Qs[row][off] = *(const f4*)(Qb + row * 64 + off);
    }
  }

  const f4 z4 = {0.f, 0.f, 0.f, 0.f};
  float m_i[2][4], l_i[2][4];
  f4 O[2][4];
#pragma unroll
  for (int rt = 0; rt < 2; ++rt)
#pragma unroll
    for (int r = 0; r < 4; ++r) { m_i[rt][r] = -1e30f; l_i[rt][r] = 0.f; }
#pragma unroll
  for (int rt = 0; rt < 2; ++rt)
#pragma unroll
    for (int dt = 0; dt < 4; ++dt) O[rt][dt] = z4;
  __syncthreads();

  for (int kk0 = 0; kk0 < 2048; kk0 += 64) {
    const _Float16* Kb = Kg + (size_t)(bh * 2048 + kk0) * 64;
    const _Float16* Vtb = Vtg + (size_t)bh * 64 * 2048 + kk0;
    for (int j = 0; j < 2; ++j) {
      int c = t + j * 256;
      int row = c >> 3, off = (c & 7) * 8;
      *(f4*)&Ks[row][off] = *(const f4*)(Kb + (size_t)row * 64 + off);
      *(f4*)&Vts[row][off] = *(const f4*)(Vtb + (size_t)row * 2048 + off);
    }
    if (t < 64) Msk[t] = (maskg[b * 2048 + kk0 + t] != 0) ? 0.f : -1e30f;
    __syncthreads();

    half8 aq[2][2];
#pragma unroll
    for (int rt = 0; rt < 2; ++rt)
#pragma unroll
      for (int ks = 0; ks < 2; ++ks)
        aq[rt][ks] = *(const half8*)&Qs[w * 32 + rt * 16 + lr][ks * 32 + qd * 8];

    f4 sc[2][4];
#pragma unroll
    for (int rt = 0; rt < 2; ++rt)
#pragma unroll
      for (int ct = 0; ct < 4; ++ct) sc[rt][ct] = z4;
#pragma unroll
    for (int ct = 0; ct < 4; ++ct) {
      half8 b0 = *(const half8*)&Ks[ct * 16 + lr][qd * 8];
      half8 b1 = *(const half8*)&Ks[ct * 16 + lr][32 + qd * 8];
#pragma unroll
      for (int rt = 0; rt < 2; ++rt) {
        sc[rt][ct] = mfma16(aq[rt][0], b0, sc[rt][ct]);
        sc[rt][ct] = mfma16(aq[rt][1], b1, sc[rt][ct]);
      }
    }

    float cm[4];
#pragma unroll
    for (int ct = 0; ct < 4; ++ct) cm[ct] = Msk[ct * 16 + lr];
#pragma unroll
    for (int rt = 0; rt < 2; ++rt)
#pragma unroll
      for (int ct = 0; ct < 4; ++ct)
#pragma unroll
        for (int r = 0; r < 4; ++r)
          sc[rt][ct][r] = sc[rt][ct][r] * 0.125f + cm[ct];

#pragma unroll
    for (int rt = 0; rt < 2; ++rt) {
      float rm[4], rs[4];
#pragma unroll
      for (int r = 0; r < 4; ++r)
        rm[r] = fmaxf(fmaxf(sc[rt][0][r], sc[rt][1][r]),
                      fmaxf(sc[rt][2][r], sc[rt][3][r]));
#pragma unroll
      for (int d = 1; d < 16; d <<= 1)
#pragma unroll
        for (int r = 0; r < 4; ++r) rm[r] = fmaxf(rm[r], __shfl_xor(rm[r], d, 64));
#pragma unroll
      for (int r = 0; r < 4; ++r) {
        float mo = m_i[rt][r];
        float mn = fmaxf(mo, rm[r]);
        m_i[rt][r] = mn;
        float a = __expf(mo - mn);
        float s = 0.f;
#pragma unroll
        for (int ct = 0; ct < 4; ++ct) {
          float p = __expf(sc[rt][ct][r] - mn);
          sc[rt][ct][r] = p;
          s += p;
        }
        rs[r] = s;
        l_i[rt][r] *= a;
#pragma unroll
        for (int dt = 0; dt < 4; ++dt) O[rt][dt][r] *= a;
      }
#pragma unroll
      for (int d = 1; d < 16; d <<= 1)
#pragma unroll
        for (int r = 0; r < 4; ++r) rs[r] += __shfl_xor(rs[r], d, 64);
#pragma unroll
      for (int r = 0; r < 4; ++r) l_i[rt][r] += rs[r];
    }

#pragma unroll
    for (int rt = 0; rt < 2; ++rt)
#pragma unroll
      for (int ct = 0; ct < 4; ++ct)
#pragma unroll
        for (int r = 0; r < 4; ++r)
          Ps[w][rt * 16 + qd * 4 + r][ct * 16 + lr] = (_Float16)sc[rt][ct][r];
    __syncthreads();  // order P write -> P read (also keeps waves in step)

    half8 ap[2][2];
#pragma unroll
    for (int rt = 0; rt < 2; ++rt)
#pragma unroll
      for (int ks = 0; ks < 2; ++ks)
        ap[rt][ks] = *(const half8*)&Ps[w][rt * 16 + lr][ks * 32 + qd * 8];
#pragma unroll
    for (int dt = 0; dt < 4; ++dt) {
      half8 b0 = *(const half8*)&Vts[dt * 16 + lr][qd * 8];
      half8 b1 = *(const half8*)&Vts[dt * 16 + lr][32 + qd * 8];
#pragma unroll
      for (int rt = 0; rt < 2; ++rt) {
        O[rt][dt] = mfma16(ap[rt][0], b0, O[rt][dt]);
        O[rt][dt] = mfma16(ap[rt][1], b1, O[rt][dt]);
      }
    }
    __syncthreads();  // before next tile overwrites Ks/Vts
  }

#pragma unroll
  for (int rt = 0; rt < 2; ++rt) {
    float inv[4];
#pragma unroll
    for (int r = 0; r < 4; ++r) inv[r] = 1.f / fmaxf(l_i[rt][r], 1e-20f);
#pragma unroll
    for (int dt = 0; dt < 4; ++dt)
#pragma unroll
      for (int r = 0; r < 4; ++r) {
        int srow = q0 + w * 32 + rt * 16 + qd * 4 + r;
        int col = h * 64 + dt * 16 + lr;
        ctx[(size_t)(b * 2048 + srow) * 1024 + col] = (_Float16)(O[rt][dt][r] * inv[r]);
      }
  }
}

// ---- 6. output projection GEMM: out = ctx @ Wo + bo (fp32 out) ----
__global__ __launch_bounds__(256) void k_gemm_out(
    const _Float16* __restrict__ A, const _Float16* __restrict__ Bt,
    const float* __restrict__ bo, float* __restrict__ out) {
  __shared__ __align__(16) _Float16 As[128 * 32];
  __shared__ __align__(16) _Float16 Bs[128 * 32];
  const int t = threadIdx.x, lane = t & 63, w = t >> 6;
  const int qd = lane >> 4, lr = lane & 15;
  const int m0 = blockIdx.y * 128, n0 = blockIdx.x * 128;
  const int wm = (w & 1) * 64, wn = (w >> 1) * 64;
  const f4 z4 = {0.f, 0.f, 0.f, 0.f};
  f4 acc[4][4];
#pragma unroll
  for (int i = 0; i < 4; ++i)
#pragma unroll
    for (int j = 0; j < 4; ++j) acc[i][j] = z4;

  const int c0 = t, c1 = t + 256;
  for (int k0 = 0; k0 < 1024; k0 += 32) {
    const _Float16* ga0 = A + (size_t)(m0 + (c0 >> 2)) * 1024 + k0 + (c0 & 3) * 8;
    const _Float16* ga1 = A + (size_t)(m0 + (c1 >> 2)) * 1024 + k0 + (c1 & 3) * 8;
    const _Float16* gb0 = Bt + (size_t)(n0 + (c0 >> 2)) * 1024 + k0 + (c0 & 3) * 8;
    const _Float16* gb1 = Bt + (size_t)(n0 + (c1 >> 2)) * 1024 + k0 + (c1 & 3) * 8;
    char* la = (char*)As + w * 1024;
    char* lb = (char*)Bs + w * 1024;
    ASYNC_COPY16(la, ga0);
    ASYNC_COPY16(la + 4096, ga1);
    ASYNC_COPY16(lb, gb0);
    ASYNC_COPY16(lb + 4096, gb1);
    __syncthreads();
    half8 af[4], bf[4];
#pragma unroll
    for (int i = 0; i < 4; ++i)
      af[i] = *(const half8*)(As + (wm + i * 16 + lr) * 32 + qd * 8);
#pragma unroll
    for (int j = 0; j < 4; ++j)
      bf[j] = *(const half8*)(Bs + (wn + j * 16 + lr) * 32 + qd * 8);
#pragma unroll
    for (int i = 0; i < 4; ++i)
#pragma unroll
      for (int j = 0; j < 4; ++j) acc[i][j] = mfma16(af[i], bf[j], acc[i][j]);
    __syncthreads();
  }
#pragma unroll
  for (int i = 0; i < 4; ++i)
#pragma unroll
    for (int j = 0; j < 4; ++j)
#pragma unroll
      for (int r = 0; r < 4; ++r) {
        int m = m0 + wm + i * 16 + qd * 4 + r;
        int n = n0 + wn + j * 16 + lr;
        out[(size_t)m * 1024 + n] = acc[i][j][r] + bo[n];
      }
}

// ---- launch ----
extern "C" void kernel_launch(void* const* d_in, const int* in_sizes, int n_in,
                              void* d_out, int out_size, void* d_ws, size_t ws_size,
                              hipStream_t stream) {
  const float* x = (const float*)d_in[0];
  const int* mask = (const int*)d_in[1];
  const float* Wq = (const float*)d_in[2];
  const float* bq = (const float*)d_in[3];
  const float* Wk = (const float*)d_in[4];
  const float* bk = (const float*)d_in[5];
  const float* Wv = (const float*)d_in[6];
  const float* bv = (const float*)d_in[7];
  const float* Wo = (const float*)d_in[8];
  const float* bo = (const float*)d_in[9];
  float* out = (float*)d_out;
  char* ws = (char*)d_ws;

  // workspace layout (bytes): total 48 MiB
  _Float16* xh    = (_Float16*)(ws + 0);         // 8 MiB; reused as ctx after proj
  _Float16* wqkvT = (_Float16*)(ws + 8388608);   // 6 MiB
  _Float16* woT   = (_Float16*)(ws + 14680064);  // 2 MiB
  _Float16* Qh    = (_Float16*)(ws + 16777216);  // 8 MiB
  _Float16* Kh    = (_Float16*)(ws + 25165824);  // 8 MiB
  _Float16* Vh    = (_Float16*)(ws + 33554432);  // 8 MiB
  _Float16* Vth   = (_Float16*)(ws + 41943040);  // 8 MiB
  _Float16* ctxh  = xh;

  k_cvt_x<<<dim3(4096), dim3(256), 0, stream>>>(x, xh);
  k_transpose_w<<<dim3(32, 32), dim3(32, 8), 0, stream>>>(Wq, wqkvT);
  k_transpose_w<<<dim3(32, 32), dim3(32, 8), 0, stream>>>(Wk, wqkvT + 1048576);
  k_transpose_w<<<dim3(32, 32), dim3(32, 8), 0, stream>>>(Wv, wqkvT + 2097152);
  k_transpose_w<<<dim3(32, 32), dim3(32, 8), 0, stream>>>(Wo, woT);
  k_gemm_proj<<<dim3(24, 32), dim3(256), 0, stream>>>(xh, wqkvT, bq, bk, bv, Qh, Kh, Vh);
  k_transpose_v<<<dim3(32, 32), dim3(256), 0, stream>>>(Vh, Vth);
  k_attn<<<dim3(16, 32), dim3(256), 0, stream>>>(Qh, Kh, Vth, mask, ctxh);
  k_gemm_out<<<dim3(8, 32), dim3(256), 0, stream>>>(ctxh, woT, bo, out);
}

// Round 2
// 260.238 us; speedup vs baseline: 1.0736x; 1.0736x over previous
//
#include <hip/hip_runtime.h>

// ---- types ----
typedef _Float16 half8 __attribute__((ext_vector_type(8)));
typedef _Float16 half4v __attribute__((ext_vector_type(4)));
typedef float f4 __attribute__((ext_vector_type(4)));

#define ASYNC_COPY16(ldsp, gp)                                                     \
  __builtin_amdgcn_global_load_lds((__attribute__((address_space(1))) void*)(gp),  \
                                   (__attribute__((address_space(3))) void*)(ldsp),\
                                   16, 0, 0)

__device__ __forceinline__ f4 mfma16(half8 a, half8 b, f4 c) {
  return __builtin_amdgcn_mfma_f32_16x16x32_f16(a, b, c, 0, 0, 0);
}

// base-2 softmax: scores scaled by 0.125*log2(e); mask add -30000
#if defined(__has_builtin)
#if __has_builtin(__builtin_amdgcn_exp2f)
#define EXP2(x) __builtin_amdgcn_exp2f(x)
#endif
#endif
#ifndef EXP2
#define EXP2(x) __expf((x) * 0.69314718056f)
#endif
#define KSCALE 0.18033688011f

// Problem constants: B=2 S=2048 E=1024 H=16 D=64, M = B*S = 4096

// ---- 1. fp32 -> fp16 cast of x ----
__global__ __launch_bounds__(256) void k_cvt_x(const float* __restrict__ x,
                                               _Float16* __restrict__ xh) {
  int i = (blockIdx.x * 256 + threadIdx.x) * 4;
  f4 v = *(const f4*)(x + i);
  half4v h;
  h[0] = (_Float16)v[0]; h[1] = (_Float16)v[1];
  h[2] = (_Float16)v[2]; h[3] = (_Float16)v[3];
  *(half4v*)(xh + i) = h;
}

// ---- 2. W [K=1024][N=1024] fp32 -> Wt [N][K] fp16 (LDS tiled transpose) ----
__global__ __launch_bounds__(256) void k_transpose_w(const float* __restrict__ w,
                                                     _Float16* __restrict__ wt) {
  __shared__ float tw[32][33];
  int k0 = blockIdx.y * 32, n0 = blockIdx.x * 32;
  int tx = threadIdx.x, ty = threadIdx.y;
  for (int j = 0; j < 32; j += 8) tw[ty + j][tx] = w[(size_t)(k0 + ty + j) * 1024 + n0 + tx];
  __syncthreads();
  for (int j = 0; j < 32; j += 8)
    wt[(size_t)(n0 + ty + j) * 1024 + k0 + tx] = (_Float16)tw[tx][ty + j];
}

// ---- 3. fused QKV projection GEMM ----
__global__ __launch_bounds__(256) void k_gemm_proj(
    const _Float16* __restrict__ A, const _Float16* __restrict__ Bt,
    const float* __restrict__ bq, const float* __restrict__ bk, const float* __restrict__ bv,
    _Float16* __restrict__ Qo, _Float16* __restrict__ Ko, _Float16* __restrict__ Vo) {
  __shared__ __align__(16) _Float16 As[128 * 32];
  __shared__ __align__(16) _Float16 Bs[128 * 32];
  const int t = threadIdx.x, lane = t & 63, w = t >> 6;
  const int qd = lane >> 4, lr = lane & 15;
  const int m0 = blockIdx.y * 128, n0 = blockIdx.x * 128;
  const int wm = (w & 1) * 64, wn = (w >> 1) * 64;
  const f4 z4 = {0.f, 0.f, 0.f, 0.f};
  f4 acc[4][4];
#pragma unroll
  for (int i = 0; i < 4; ++i)
#pragma unroll
    for (int j = 0; j < 4; ++j) acc[i][j] = z4;

  const int c0 = t, c1 = t + 256;
  for (int k0 = 0; k0 < 1024; k0 += 32) {
    const _Float16* ga0 = A + (size_t)(m0 + (c0 >> 2)) * 1024 + k0 + (c0 & 3) * 8;
    const _Float16* ga1 = A + (size_t)(m0 + (c1 >> 2)) * 1024 + k0 + (c1 & 3) * 8;
    const _Float16* gb0 = Bt + (size_t)(n0 + (c0 >> 2)) * 1024 + k0 + (c0 & 3) * 8;
    const _Float16* gb1 = Bt + (size_t)(n0 + (c1 >> 2)) * 1024 + k0 + (c1 & 3) * 8;
    char* la = (char*)As + w * 1024;
    char* lb = (char*)Bs + w * 1024;
    ASYNC_COPY16(la, ga0);
    ASYNC_COPY16(la + 4096, ga1);
    ASYNC_COPY16(lb, gb0);
    ASYNC_COPY16(lb + 4096, gb1);
    __syncthreads();
    half8 af[4], bf[4];
#pragma unroll
    for (int i = 0; i < 4; ++i)
      af[i] = *(const half8*)(As + (wm + i * 16 + lr) * 32 + qd * 8);
#pragma unroll
    for (int j = 0; j < 4; ++j)
      bf[j] = *(const half8*)(Bs + (wn + j * 16 + lr) * 32 + qd * 8);
#pragma unroll
    for (int i = 0; i < 4; ++i)
#pragma unroll
      for (int j = 0; j < 4; ++j) acc[i][j] = mfma16(af[i], bf[j], acc[i][j]);
    __syncthreads();
  }

  const int mat = n0 >> 10;
  const float* bias = (mat == 0) ? bq : (mat == 1) ? bk : bv;
  _Float16* outp = (mat == 0) ? Qo : (mat == 1) ? Ko : Vo;
#pragma unroll
  for (int i = 0; i < 4; ++i)
#pragma unroll
    for (int j = 0; j < 4; ++j)
#pragma unroll
      for (int r = 0; r < 4; ++r) {
        int m = m0 + wm + i * 16 + qd * 4 + r;
        int n = (n0 + wn + j * 16 + lr) & 1023;
        float v = acc[i][j][r] + bias[n];
        int bb = m >> 11, s = m & 2047, hh = n >> 6, d = n & 63;
        outp[(size_t)((bb * 16 + hh) * 2048 + s) * 64 + d] = (_Float16)v;
      }
}

// ---- 4. V [B,H,S,D] -> Vt [B,H,D,S] ----
__global__ __launch_bounds__(256) void k_transpose_v(const _Float16* __restrict__ V,
                                                     _Float16* __restrict__ Vt) {
  __shared__ __align__(16) _Float16 tv[64][72];
  int bh = blockIdx.y, s0 = blockIdx.x * 64;
  int t = threadIdx.x;
  const _Float16* vb = V + (size_t)(bh * 2048 + s0) * 64;
  for (int j = 0; j < 2; ++j) {
    int c = t + j * 256;
    int row = c >> 3, off = (c & 7) * 8;
    *(f4*)&tv[row][off] = *(const f4*)(vb + row * 64 + off);
  }
  __syncthreads();
  _Float16* ob = Vt + (size_t)bh * 64 * 2048 + s0;
  for (int j = 0; j < 2; ++j) {
    int c = t + j * 256;
    int d = c >> 3, so = (c & 7) * 8;
    half8 h;
#pragma unroll
    for (int u = 0; u < 8; ++u) h[u] = tv[so + u][d];
    *(half8*)(ob + (size_t)d * 2048 + so) = h;
  }
}

// ---- 5. flash attention, S^T formulation ----
// S^T = K·Q^T (m=k, n=q), softmax reduces in-lane + 2 shuffles, O^T = Vt·P^T.
// Q fragments hoisted to registers (no Qs LDS); Pq per-wave (no barrier);
// K/V/mask prefetched into registers to overlap global latency with compute.
__global__ __launch_bounds__(256, 4) void k_attn(
    const _Float16* __restrict__ Qg, const _Float16* __restrict__ Kg,
    const _Float16* __restrict__ Vtg, const int* __restrict__ maskg,
    _Float16* __restrict__ ctx) {
  __shared__ __align__(16) _Float16 Ks[64][72];
  __shared__ __align__(16) _Float16 Vts[64][72];
  __shared__ __align__(16) _Float16 Pq[4][32][72];
  __shared__ float Msk[64];

  const int bh = blockIdx.y;
  const int b = bh >> 4, h = bh & 15;
  const int q0 = blockIdx.x * 128;
  const int t = threadIdx.x, lane = t & 63, w = t >> 6;
  const int qd = lane >> 4, lr = lane & 15;

  // hoisted Q b-fragments: B[k=d][n=q=lr] = Q[q][d]
  half8 qf[2][2];
#pragma unroll
  for (int rt = 0; rt < 2; ++rt)
#pragma unroll
    for (int ks = 0; ks < 2; ++ks)
      qf[rt][ks] = *(const half8*)(Qg + (size_t)(bh * 2048 + q0 + w * 32 + rt * 16 + lr) * 64 +
                                   ks * 32 + qd * 8);

  float m_i[2] = {-1e30f, -1e30f}, l_i[2] = {0.f, 0.f};
  const f4 z4 = {0.f, 0.f, 0.f, 0.f};
  f4 O[2][4];
#pragma unroll
  for (int rt = 0; rt < 2; ++rt)
#pragma unroll
    for (int dt = 0; dt < 4; ++dt) O[rt][dt] = z4;

  const int sr0 = t >> 3, scc = (t & 7) * 8;  // staging row/col
  const int sr1 = sr0 + 32;
  const _Float16* Kbase = Kg + (size_t)bh * 2048 * 64;
  const _Float16* Vtbase = Vtg + (size_t)bh * 64 * 2048;

  // prefetch tile 0
  f4 kr0 = *(const f4*)(Kbase + (size_t)sr0 * 64 + scc);
  f4 kr1 = *(const f4*)(Kbase + (size_t)sr1 * 64 + scc);
  f4 vr0 = *(const f4*)(Vtbase + (size_t)sr0 * 2048 + scc);
  f4 vr1 = *(const f4*)(Vtbase + (size_t)sr1 * 2048 + scc);
  float mval = 0.f;
  if (t < 64) mval = maskg[b * 2048 + t] ? 0.f : -30000.f;

  for (int it = 0; it < 32; ++it) {
    __syncthreads();  // previous tile's LDS reads complete
    *(f4*)&Ks[sr0][scc] = kr0;
    *(f4*)&Ks[sr1][scc] = kr1;
    *(f4*)&Vts[sr0][scc] = vr0;
    *(f4*)&Vts[sr1][scc] = vr1;
    if (t < 64) Msk[t] = mval;
    __syncthreads();  // LDS ready

    if (it < 31) {  // prefetch next tile (overlaps compute)
      int kk = (it + 1) * 64;
      kr0 = *(const f4*)(Kbase + (size_t)(kk + sr0) * 64 + scc);
      kr1 = *(const f4*)(Kbase + (size_t)(kk + sr1) * 64 + scc);
      vr0 = *(const f4*)(Vtbase + (size_t)sr0 * 2048 + kk + scc);
      vr1 = *(const f4*)(Vtbase + (size_t)sr1 * 2048 + kk + scc);
      if (t < 64) mval = maskg[b * 2048 + kk + t] ? 0.f : -30000.f;
    }

    // S^T = K·Q^T : A-frag = K rows (m = k-local), B-frag = qf
    f4 sc[2][4];
#pragma unroll
    for (int rt = 0; rt < 2; ++rt)
#pragma unroll
      for (int kt = 0; kt < 4; ++kt) sc[rt][kt] = z4;
#pragma unroll
    for (int kt = 0; kt < 4; ++kt) {
      half8 k0 = *(const half8*)&Ks[kt * 16 + lr][qd * 8];
      half8 k1 = *(const half8*)&Ks[kt * 16 + lr][32 + qd * 8];
      sc[0][kt] = mfma16(k0, qf[0][0], sc[0][kt]);
      sc[0][kt] = mfma16(k1, qf[0][1], sc[0][kt]);
      sc[1][kt] = mfma16(k0, qf[1][0], sc[1][kt]);
      sc[1][kt] = mfma16(k1, qf[1][1], sc[1][kt]);
    }

    // scale (log2-space) + additive mask; k-local = kt*16 + qd*4 + r
#pragma unroll
    for (int kt = 0; kt < 4; ++kt) {
      f4 mv = *(const f4*)&Msk[kt * 16 + qd * 4];
#pragma unroll
      for (int r = 0; r < 4; ++r) {
        sc[0][kt][r] = sc[0][kt][r] * KSCALE + mv[r];
        sc[1][kt][r] = sc[1][kt][r] * KSCALE + mv[r];
      }
    }

    // online softmax: each lane owns q = lr for both rt
#pragma unroll
    for (int rt = 0; rt < 2; ++rt) {
      float mx = sc[rt][0][0];
#pragma unroll
      for (int kt = 0; kt < 4; ++kt)
#pragma unroll
        for (int r = 0; r < 4; ++r) mx = fmaxf(mx, sc[rt][kt][r]);
      mx = fmaxf(mx, __shfl_xor(mx, 16, 64));
      mx = fmaxf(mx, __shfl_xor(mx, 32, 64));
      float mn = fmaxf(m_i[rt], mx);
      float alpha = EXP2(m_i[rt] - mn);
      m_i[rt] = mn;
      float s = 0.f;
#pragma unroll
      for (int kt = 0; kt < 4; ++kt)
#pragma unroll
        for (int r = 0; r < 4; ++r) {
          float p = EXP2(sc[rt][kt][r] - mn);
          sc[rt][kt][r] = p;
          s += p;
        }
      s += __shfl_xor(s, 16, 64);
      s += __shfl_xor(s, 32, 64);
      l_i[rt] = l_i[rt] * alpha + s;
#pragma unroll
      for (int dt = 0; dt < 4; ++dt)
#pragma unroll
        for (int r = 0; r < 4; ++r) O[rt][dt][r] *= alpha;
      // P^T stored as Pq[q][k]: lane writes 4 consecutive k -> b64, conflict-free
#pragma unroll
      for (int kt = 0; kt < 4; ++kt) {
        half4v hv;
        hv[0] = (_Float16)sc[rt][kt][0];
        hv[1] = (_Float16)sc[rt][kt][1];
        hv[2] = (_Float16)sc[rt][kt][2];
        hv[3] = (_Float16)sc[rt][kt][3];
        *(half4v*)&Pq[w][rt * 16 + lr][kt * 16 + qd * 4] = hv;
      }
    }

    // O^T += Vt·P^T (Pq is per-wave: no barrier, lgkmcnt ordering suffices)
#pragma unroll
    for (int ks = 0; ks < 2; ++ks) {
      half8 bp0 = *(const half8*)&Pq[w][lr][ks * 32 + qd * 8];
      half8 bp1 = *(const half8*)&Pq[w][16 + lr][ks * 32 + qd * 8];
#pragma unroll
      for (int dt = 0; dt < 4; ++dt) {
        half8 va = *(const half8*)&Vts[dt * 16 + lr][ks * 32 + qd * 8];
        O[0][dt] = mfma16(va, bp0, O[0][dt]);
        O[1][dt] = mfma16(va, bp1, O[1][dt]);
      }
    }
  }

  // epilogue: O^T[d][q] -> ctx[q][h*64+d], 8B stores
#pragma unroll
  for (int rt = 0; rt < 2; ++rt) {
    float inv = 1.f / fmaxf(l_i[rt], 1e-20f);
    int qrow = q0 + w * 32 + rt * 16 + lr;
    _Float16* cp = ctx + (size_t)(b * 2048 + qrow) * 1024 + h * 64;
#pragma unroll
    for (int dt = 0; dt < 4; ++dt) {
      half4v hv;
#pragma unroll
      for (int r = 0; r < 4; ++r) hv[r] = (_Float16)(O[rt][dt][r] * inv);
      *(half4v*)(cp + dt * 16 + qd * 4) = hv;
    }
  }
}

// ---- 6. output projection GEMM: out = ctx @ Wo + bo (fp32 out) ----
__global__ __launch_bounds__(256) void k_gemm_out(
    const _Float16* __restrict__ A, const _Float16* __restrict__ Bt,
    const float* __restrict__ bo, float* __restrict__ out) {
  __shared__ __align__(16) _Float16 As[128 * 32];
  __shared__ __align__(16) _Float16 Bs[128 * 32];
  const int t = threadIdx.x, lane = t & 63, w = t >> 6;
  const int qd = lane >> 4, lr = lane & 15;
  const int m0 = blockIdx.y * 128, n0 = blockIdx.x * 128;
  const int wm = (w & 1) * 64, wn = (w >> 1) * 64;
  const f4 z4 = {0.f, 0.f, 0.f, 0.f};
  f4 acc[4][4];
#pragma unroll
  for (int i = 0; i < 4; ++i)
#pragma unroll
    for (int j = 0; j < 4; ++j) acc[i][j] = z4;

  const int c0 = t, c1 = t + 256;
  for (int k0 = 0; k0 < 1024; k0 += 32) {
    const _Float16* ga0 = A + (size_t)(m0 + (c0 >> 2)) * 1024 + k0 + (c0 & 3) * 8;
    const _Float16* ga1 = A + (size_t)(m0 + (c1 >> 2)) * 1024 + k0 + (c1 & 3) * 8;
    const _Float16* gb0 = Bt + (size_t)(n0 + (c0 >> 2)) * 1024 + k0 + (c0 & 3) * 8;
    const _Float16* gb1 = Bt + (size_t)(n0 + (c1 >> 2)) * 1024 + k0 + (c1 & 3) * 8;
    char* la = (char*)As + w * 1024;
    char* lb = (char*)Bs + w * 1024;
    ASYNC_COPY16(la, ga0);
    ASYNC_COPY16(la + 4096, ga1);
    ASYNC_COPY16(lb, gb0);
    ASYNC_COPY16(lb + 4096, gb1);
    __syncthreads();
    half8 af[4], bf[4];
#pragma unroll
    for (int i = 0; i < 4; ++i)
      af[i] = *(const half8*)(As + (wm + i * 16 + lr) * 32 + qd * 8);
#pragma unroll
    for (int j = 0; j < 4; ++j)
      bf[j] = *(const half8*)(Bs + (wn + j * 16 + lr) * 32 + qd * 8);
#pragma unroll
    for (int i = 0; i < 4; ++i)
#pragma unroll
      for (int j = 0; j < 4; ++j) acc[i][j] = mfma16(af[i], bf[j], acc[i][j]);
    __syncthreads();
  }
#pragma unroll
  for (int i = 0; i < 4; ++i)
#pragma unroll
    for (int j = 0; j < 4; ++j)
#pragma unroll
      for (int r = 0; r < 4; ++r) {
        int m = m0 + wm + i * 16 + qd * 4 + r;
        int n = n0 + wn + j * 16 + lr;
        out[(size_t)m * 1024 + n] = acc[i][j][r] + bo[n];
      }
}

// ---- launch ----
extern "C" void kernel_launch(void* const* d_in, const int* in_sizes, int n_in,
                              void* d_out, int out_size, void* d_ws, size_t ws_size,
                              hipStream_t stream) {
  const float* x = (const float*)d_in[0];
  const int* mask = (const int*)d_in[1];
  const float* Wq = (const float*)d_in[2];
  const float* bq = (const float*)d_in[3];
  const float* Wk = (const float*)d_in[4];
  const float* bk = (const float*)d_in[5];
  const float* Wv = (const float*)d_in[6];
  const float* bv = (const float*)d_in[7];
  const float* Wo = (const float*)d_in[8];
  const float* bo = (const float*)d_in[9];
  float* out = (float*)d_out;
  char* ws = (char*)d_ws;

  _Float16* xh    = (_Float16*)(ws + 0);         // 8 MiB; reused as ctx after proj
  _Float16* wqkvT = (_Float16*)(ws + 8388608);   // 6 MiB
  _Float16* woT   = (_Float16*)(ws + 14680064);  // 2 MiB
  _Float16* Qh    = (_Float16*)(ws + 16777216);  // 8 MiB
  _Float16* Kh    = (_Float16*)(ws + 25165824);  // 8 MiB
  _Float16* Vh    = (_Float16*)(ws + 33554432);  // 8 MiB
  _Float16* Vth   = (_Float16*)(ws + 41943040);  // 8 MiB
  _Float16* ctxh  = xh;

  k_cvt_x<<<dim3(4096), dim3(256), 0, stream>>>(x, xh);
  k_transpose_w<<<dim3(32, 32), dim3(32, 8), 0, stream>>>(Wq, wqkvT);
  k_transpose_w<<<dim3(32, 32), dim3(32, 8), 0, stream>>>(Wk, wqkvT + 1048576);
  k_transpose_w<<<dim3(32, 32), dim3(32, 8), 0, stream>>>(Wv, wqkvT + 2097152);
  k_transpose_w<<<dim3(32, 32), dim3(32, 8), 0, stream>>>(Wo, woT);
  k_gemm_proj<<<dim3(24, 32), dim3(256), 0, stream>>>(xh, wqkvT, bq, bk, bv, Qh, Kh, Vh);
  k_transpose_v<<<dim3(32, 32), dim3(256), 0, stream>>>(Vh, Vth);
  k_attn<<<dim3(16, 32), dim3(256), 0, stream>>>(Qh, Kh, Vth, mask, ctxh);
  k_gemm_out<<<dim3(8, 32), dim3(256), 0, stream>>>(ctxh, woT, bo, out);
}

// Round 3
// 217.278 us; speedup vs baseline: 1.2858x; 1.1977x over previous
//
#include <hip/hip_runtime.h>

// ---- types ----
typedef _Float16 half8 __attribute__((ext_vector_type(8)));
typedef _Float16 half4v __attribute__((ext_vector_type(4)));
typedef float f4 __attribute__((ext_vector_type(4)));

#define ASYNC_COPY16(ldsp, gp)                                                     \
  __builtin_amdgcn_global_load_lds((__attribute__((address_space(1))) void*)(gp),  \
                                   (__attribute__((address_space(3))) void*)(ldsp),\
                                   16, 0, 0)

__device__ __forceinline__ f4 mfma16(half8 a, half8 b, f4 c) {
  return __builtin_amdgcn_mfma_f32_16x16x32_f16(a, b, c, 0, 0, 0);
}

// base-2 softmax: Q pre-scaled by 0.125*log2(e); mask add -30000 (log2 domain)
#if defined(__has_builtin)
#if __has_builtin(__builtin_amdgcn_exp2f)
#define EXP2(x) __builtin_amdgcn_exp2f(x)
#endif
#endif
#ifndef EXP2
#define EXP2(x) __expf((x) * 0.69314718056f)
#endif
#define KSCALE 0.18033688011f

// Problem constants: B=2 S=2048 E=1024 H=16 D=64, M = B*S = 4096

// ---- 1. fp32 -> fp16 cast of x ----
__global__ __launch_bounds__(256) void k_cvt_x(const float* __restrict__ x,
                                               _Float16* __restrict__ xh) {
  int i = (blockIdx.x * 256 + threadIdx.x) * 4;
  f4 v = *(const f4*)(x + i);
  half4v h;
  h[0] = (_Float16)v[0]; h[1] = (_Float16)v[1];
  h[2] = (_Float16)v[2]; h[3] = (_Float16)v[3];
  *(half4v*)(xh + i) = h;
}

// ---- 2. fused weight transposes: W[K][N] fp32 -> Wt[N][K] fp16, z picks matrix ----
__global__ __launch_bounds__(256) void k_transpose_w(
    const float* __restrict__ Wq, const float* __restrict__ Wk,
    const float* __restrict__ Wv, const float* __restrict__ Wo,
    _Float16* __restrict__ wqkvT, _Float16* __restrict__ woT) {
  __shared__ float tw[32][33];
  int z = blockIdx.z;
  const float* w = (z == 0) ? Wq : (z == 1) ? Wk : (z == 2) ? Wv : Wo;
  _Float16* wt = (z == 3) ? woT : wqkvT + (size_t)z * 1048576;
  int k0 = blockIdx.y * 32, n0 = blockIdx.x * 32;
  int tx = threadIdx.x, ty = threadIdx.y;
  for (int j = 0; j < 32; j += 8) tw[ty + j][tx] = w[(size_t)(k0 + ty + j) * 1024 + n0 + tx];
  __syncthreads();
  for (int j = 0; j < 32; j += 8)
    wt[(size_t)(n0 + ty + j) * 1024 + k0 + tx] = (_Float16)tw[tx][ty + j];
}

// ---- 3. fused QKV projection GEMM ----
// Q gets *KSCALE folded in; V is written transposed [B,H,D,S].
__global__ __launch_bounds__(256) void k_gemm_proj(
    const _Float16* __restrict__ A, const _Float16* __restrict__ Bt,
    const float* __restrict__ bq, const float* __restrict__ bk, const float* __restrict__ bv,
    _Float16* __restrict__ Qo, _Float16* __restrict__ Ko, _Float16* __restrict__ Vto) {
  __shared__ __align__(16) _Float16 As[128 * 32];
  __shared__ __align__(16) _Float16 Bs[128 * 32];
  const int t = threadIdx.x, lane = t & 63, w = t >> 6;
  const int qd = lane >> 4, lr = lane & 15;
  const int m0 = blockIdx.y * 128, n0 = blockIdx.x * 128;
  const int wm = (w & 1) * 64, wn = (w >> 1) * 64;
  const f4 z4 = {0.f, 0.f, 0.f, 0.f};
  f4 acc[4][4];
#pragma unroll
  for (int i = 0; i < 4; ++i)
#pragma unroll
    for (int j = 0; j < 4; ++j) acc[i][j] = z4;

  const int c0 = t, c1 = t + 256;
  for (int k0 = 0; k0 < 1024; k0 += 32) {
    const _Float16* ga0 = A + (size_t)(m0 + (c0 >> 2)) * 1024 + k0 + (c0 & 3) * 8;
    const _Float16* ga1 = A + (size_t)(m0 + (c1 >> 2)) * 1024 + k0 + (c1 & 3) * 8;
    const _Float16* gb0 = Bt + (size_t)(n0 + (c0 >> 2)) * 1024 + k0 + (c0 & 3) * 8;
    const _Float16* gb1 = Bt + (size_t)(n0 + (c1 >> 2)) * 1024 + k0 + (c1 & 3) * 8;
    char* la = (char*)As + w * 1024;
    char* lb = (char*)Bs + w * 1024;
    ASYNC_COPY16(la, ga0);
    ASYNC_COPY16(la + 4096, ga1);
    ASYNC_COPY16(lb, gb0);
    ASYNC_COPY16(lb + 4096, gb1);
    __syncthreads();
    half8 af[4], bf[4];
#pragma unroll
    for (int i = 0; i < 4; ++i)
      af[i] = *(const half8*)(As + (wm + i * 16 + lr) * 32 + qd * 8);
#pragma unroll
    for (int j = 0; j < 4; ++j)
      bf[j] = *(const half8*)(Bs + (wn + j * 16 + lr) * 32 + qd * 8);
#pragma unroll
    for (int i = 0; i < 4; ++i)
#pragma unroll
      for (int j = 0; j < 4; ++j) acc[i][j] = mfma16(af[i], bf[j], acc[i][j]);
    __syncthreads();
  }

  const int mat = n0 >> 10;
  const float* bias = (mat == 0) ? bq : (mat == 1) ? bk : bv;
  if (mat == 2) {
    // V: transposed store [bh][d][s], 4 consecutive s per half4v
#pragma unroll
    for (int i = 0; i < 4; ++i)
#pragma unroll
      for (int j = 0; j < 4; ++j) {
        int n = (n0 + wn + j * 16 + lr) & 1023;
        int hh = n >> 6, d = n & 63;
        int mb = m0 + wm + i * 16 + qd * 4;
        int bb = mb >> 11, sb = mb & 2047;
        float bval = bias[n];
        half4v hv;
#pragma unroll
        for (int r = 0; r < 4; ++r) hv[r] = (_Float16)(acc[i][j][r] + bval);
        *(half4v*)(Vto + ((size_t)(bb * 16 + hh) * 64 + d) * 2048 + sb) = hv;
      }
  } else {
    _Float16* outp = (mat == 0) ? Qo : Ko;
    const float scl = (mat == 0) ? KSCALE : 1.f;
#pragma unroll
    for (int i = 0; i < 4; ++i)
#pragma unroll
      for (int j = 0; j < 4; ++j)
#pragma unroll
        for (int r = 0; r < 4; ++r) {
          int m = m0 + wm + i * 16 + qd * 4 + r;
          int n = (n0 + wn + j * 16 + lr) & 1023;
          float v = (acc[i][j][r] + bias[n]) * scl;
          int bb = m >> 11, s = m & 2047, hh = n >> 6, d = n & 63;
          outp[(size_t)((bb * 16 + hh) * 2048 + s) * 64 + d] = (_Float16)v;
        }
  }
}

// ---- 4. flash attention, S^T formulation, k-split x2 ----
// blockIdx.z = split; each block covers 1024 keys. Writes unnormalized O (fp16)
// plus per-row (m, l) fp32 for the merge kernel. Mask folded into MFMA acc init;
// scale pre-folded into Q; alpha-rescale skipped via wave ballot when max static.
__global__ __launch_bounds__(256, 4) void k_attn(
    const _Float16* __restrict__ Qg, const _Float16* __restrict__ Kg,
    const _Float16* __restrict__ Vtg, const int* __restrict__ maskg,
    _Float16* __restrict__ Op, float* __restrict__ ml) {
  __shared__ __align__(16) _Float16 Ks[64][72];
  __shared__ __align__(16) _Float16 Vts[64][72];
  __shared__ __align__(16) _Float16 Pq[4][32][72];
  __shared__ float Msk[64];

  const int bh = blockIdx.y;
  const int b = bh >> 4;
  const int q0 = blockIdx.x * 128;
  const int z = blockIdx.z;
  const int kb = z * 1024;
  const int t = threadIdx.x, lane = t & 63, w = t >> 6;
  const int qd = lane >> 4, lr = lane & 15;

  half8 qf[2][2];
#pragma unroll
  for (int rt = 0; rt < 2; ++rt)
#pragma unroll
    for (int ks = 0; ks < 2; ++ks)
      qf[rt][ks] = *(const half8*)(Qg + (size_t)(bh * 2048 + q0 + w * 32 + rt * 16 + lr) * 64 +
                                   ks * 32 + qd * 8);

  float m_i[2] = {-1e30f, -1e30f}, l_i[2] = {0.f, 0.f};
  const f4 z4 = {0.f, 0.f, 0.f, 0.f};
  f4 O[2][4];
#pragma unroll
  for (int rt = 0; rt < 2; ++rt)
#pragma unroll
    for (int dt = 0; dt < 4; ++dt) O[rt][dt] = z4;

  const int sr0 = t >> 3, scc = (t & 7) * 8;
  const int sr1 = sr0 + 32;
  const _Float16* Kbase = Kg + (size_t)bh * 2048 * 64 + (size_t)kb * 64;
  const _Float16* Vtbase = Vtg + (size_t)bh * 64 * 2048 + kb;

  f4 kr0 = *(const f4*)(Kbase + (size_t)sr0 * 64 + scc);
  f4 kr1 = *(const f4*)(Kbase + (size_t)sr1 * 64 + scc);
  f4 vr0 = *(const f4*)(Vtbase + (size_t)sr0 * 2048 + scc);
  f4 vr1 = *(const f4*)(Vtbase + (size_t)sr1 * 2048 + scc);
  float mval = 0.f;
  if (t < 64) mval = maskg[b * 2048 + kb + t] ? 0.f : -30000.f;

  for (int it = 0; it < 16; ++it) {
    __syncthreads();
    *(f4*)&Ks[sr0][scc] = kr0;
    *(f4*)&Ks[sr1][scc] = kr1;
    *(f4*)&Vts[sr0][scc] = vr0;
    *(f4*)&Vts[sr1][scc] = vr1;
    if (t < 64) Msk[t] = mval;
    __syncthreads();

    if (it < 15) {
      int kk = (it + 1) * 64;
      kr0 = *(const f4*)(Kbase + (size_t)(kk + sr0) * 64 + scc);
      kr1 = *(const f4*)(Kbase + (size_t)(kk + sr1) * 64 + scc);
      vr0 = *(const f4*)(Vtbase + (size_t)sr0 * 2048 + kk + scc);
      vr1 = *(const f4*)(Vtbase + (size_t)sr1 * 2048 + kk + scc);
      if (t < 64) mval = maskg[b * 2048 + kb + kk + t] ? 0.f : -30000.f;
    }

    // S^T = K·Qs^T + mask (mask in acc init; scale folded into Q)
    f4 sc[2][4];
#pragma unroll
    for (int kt = 0; kt < 4; ++kt) {
      f4 mv = *(const f4*)&Msk[kt * 16 + qd * 4];
      sc[0][kt] = mv;
      sc[1][kt] = mv;
    }
#pragma unroll
    for (int kt = 0; kt < 4; ++kt) {
      half8 k0 = *(const half8*)&Ks[kt * 16 + lr][qd * 8];
      half8 k1 = *(const half8*)&Ks[kt * 16 + lr][32 + qd * 8];
      sc[0][kt] = mfma16(k0, qf[0][0], sc[0][kt]);
      sc[0][kt] = mfma16(k1, qf[0][1], sc[0][kt]);
      sc[1][kt] = mfma16(k0, qf[1][0], sc[1][kt]);
      sc[1][kt] = mfma16(k1, qf[1][1], sc[1][kt]);
    }

    // online softmax: each lane owns q = lr for both rt (log2 domain)
#pragma unroll
    for (int rt = 0; rt < 2; ++rt) {
      float mx = sc[rt][0][0];
#pragma unroll
      for (int kt = 0; kt < 4; ++kt)
#pragma unroll
        for (int r = 0; r < 4; ++r) mx = fmaxf(mx, sc[rt][kt][r]);
      mx = fmaxf(mx, __shfl_xor(mx, 16, 64));
      mx = fmaxf(mx, __shfl_xor(mx, 32, 64));
      if (__ballot(mx > m_i[rt]) != 0ULL) {  // wave-uniform: rescale only if some lane's max moved
        float mn = fmaxf(m_i[rt], mx);
        float alpha = EXP2(m_i[rt] - mn);
        m_i[rt] = mn;
        l_i[rt] *= alpha;
#pragma unroll
        for (int dt = 0; dt < 4; ++dt)
#pragma unroll
          for (int r = 0; r < 4; ++r) O[rt][dt][r] *= alpha;
      }
      float mn = m_i[rt];
      float s = 0.f;
#pragma unroll
      for (int kt = 0; kt < 4; ++kt)
#pragma unroll
        for (int r = 0; r < 4; ++r) {
          float p = EXP2(sc[rt][kt][r] - mn);
          sc[rt][kt][r] = p;
          s += p;
        }
      s += __shfl_xor(s, 16, 64);
      s += __shfl_xor(s, 32, 64);
      l_i[rt] += s;
#pragma unroll
      for (int kt = 0; kt < 4; ++kt) {
        half4v hv;
        hv[0] = (_Float16)sc[rt][kt][0];
        hv[1] = (_Float16)sc[rt][kt][1];
        hv[2] = (_Float16)sc[rt][kt][2];
        hv[3] = (_Float16)sc[rt][kt][3];
        *(half4v*)&Pq[w][rt * 16 + lr][kt * 16 + qd * 4] = hv;
      }
    }

    // O^T += Vt·P^T (Pq per-wave: no barrier needed)
#pragma unroll
    for (int ks = 0; ks < 2; ++ks) {
      half8 bp0 = *(const half8*)&Pq[w][lr][ks * 32 + qd * 8];
      half8 bp1 = *(const half8*)&Pq[w][16 + lr][ks * 32 + qd * 8];
#pragma unroll
      for (int dt = 0; dt < 4; ++dt) {
        half8 va = *(const half8*)&Vts[dt * 16 + lr][ks * 32 + qd * 8];
        O[0][dt] = mfma16(va, bp0, O[0][dt]);
        O[1][dt] = mfma16(va, bp1, O[1][dt]);
      }
    }
  }

  // epilogue: unnormalized partials + (m,l)
#pragma unroll
  for (int rt = 0; rt < 2; ++rt) {
    int qrow = q0 + w * 32 + rt * 16 + lr;
    size_t rowi = (size_t)(z * 32 + bh) * 2048 + qrow;
    _Float16* op = Op + rowi * 64;
#pragma unroll
    for (int dt = 0; dt < 4; ++dt) {
      half4v hv;
#pragma unroll
      for (int r = 0; r < 4; ++r) hv[r] = (_Float16)O[rt][dt][r];
      *(half4v*)(op + dt * 16 + qd * 4) = hv;
    }
    if (qd == 0) {
      ml[rowi * 2] = m_i[rt];
      ml[rowi * 2 + 1] = l_i[rt];
    }
  }
}

// ---- 5. split-merge: ctx = (w1*O1 + w2*O2) / (w1*l1 + w2*l2) ----
__global__ __launch_bounds__(256) void k_merge(const _Float16* __restrict__ Op,
                                               const float* __restrict__ ml,
                                               _Float16* __restrict__ ctx) {
  int idx = blockIdx.x * 256 + threadIdx.x;
  int d8 = (idx & 7) * 8;
  int h = (idx >> 3) & 15;
  int q = idx >> 7;  // 0..4095
  int b = q >> 11, s = q & 2047;
  int bh = b * 16 + h;
  size_t r1 = (size_t)bh * 2048 + s;
  size_t r2 = (size_t)(32 + bh) * 2048 + s;
  float m1 = ml[r1 * 2], l1 = ml[r1 * 2 + 1];
  float m2 = ml[r2 * 2], l2 = ml[r2 * 2 + 1];
  float M = fmaxf(m1, m2);
  float w1 = EXP2(m1 - M), w2 = EXP2(m2 - M);
  float inv = 1.f / fmaxf(w1 * l1 + w2 * l2, 1e-20f);
  half8 o1 = *(const half8*)(Op + r1 * 64 + d8);
  half8 o2 = *(const half8*)(Op + r2 * 64 + d8);
  half8 ho;
#pragma unroll
  for (int j = 0; j < 8; ++j)
    ho[j] = (_Float16)((w1 * (float)o1[j] + w2 * (float)o2[j]) * inv);
  *(half8*)(ctx + (size_t)q * 1024 + h * 64 + d8) = ho;
}

// ---- 6. output projection GEMM: 64x128 tiles -> 512 blocks (2/CU) ----
__global__ __launch_bounds__(256) void k_gemm_out(
    const _Float16* __restrict__ A, const _Float16* __restrict__ Bt,
    const float* __restrict__ bo, float* __restrict__ out) {
  __shared__ __align__(16) _Float16 As[64 * 32];
  __shared__ __align__(16) _Float16 Bs[128 * 32];
  const int t = threadIdx.x, lane = t & 63, w = t >> 6;
  const int qd = lane >> 4, lr = lane & 15;
  const int m0 = blockIdx.y * 64, n0 = blockIdx.x * 128;
  const int wm = (w & 1) * 32, wn = (w >> 1) * 64;
  const f4 z4 = {0.f, 0.f, 0.f, 0.f};
  f4 acc[2][4];
#pragma unroll
  for (int i = 0; i < 2; ++i)
#pragma unroll
    for (int j = 0; j < 4; ++j) acc[i][j] = z4;

  const int c0 = t, c1 = t + 256;
  for (int k0 = 0; k0 < 1024; k0 += 32) {
    const _Float16* ga = A + (size_t)(m0 + (t >> 2)) * 1024 + k0 + (t & 3) * 8;
    const _Float16* gb0 = Bt + (size_t)(n0 + (c0 >> 2)) * 1024 + k0 + (c0 & 3) * 8;
    const _Float16* gb1 = Bt + (size_t)(n0 + (c1 >> 2)) * 1024 + k0 + (c1 & 3) * 8;
    char* la = (char*)As + w * 1024;
    char* lb = (char*)Bs + w * 1024;
    ASYNC_COPY16(la, ga);
    ASYNC_COPY16(lb, gb0);
    ASYNC_COPY16(lb + 4096, gb1);
    __syncthreads();
    half8 af[2], bf[4];
#pragma unroll
    for (int i = 0; i < 2; ++i)
      af[i] = *(const half8*)(As + (wm + i * 16 + lr) * 32 + qd * 8);
#pragma unroll
    for (int j = 0; j < 4; ++j)
      bf[j] = *(const half8*)(Bs + (wn + j * 16 + lr) * 32 + qd * 8);
#pragma unroll
    for (int i = 0; i < 2; ++i)
#pragma unroll
      for (int j = 0; j < 4; ++j) acc[i][j] = mfma16(af[i], bf[j], acc[i][j]);
    __syncthreads();
  }
#pragma unroll
  for (int i = 0; i < 2; ++i)
#pragma unroll
    for (int j = 0; j < 4; ++j)
#pragma unroll
      for (int r = 0; r < 4; ++r) {
        int m = m0 + wm + i * 16 + qd * 4 + r;
        int n = n0 + wn + j * 16 + lr;
        out[(size_t)m * 1024 + n] = acc[i][j][r] + bo[n];
      }
}

// ---- launch ----
extern "C" void kernel_launch(void* const* d_in, const int* in_sizes, int n_in,
                              void* d_out, int out_size, void* d_ws, size_t ws_size,
                              hipStream_t stream) {
  const float* x = (const float*)d_in[0];
  const int* mask = (const int*)d_in[1];
  const float* Wq = (const float*)d_in[2];
  const float* bq = (const float*)d_in[3];
  const float* Wk = (const float*)d_in[4];
  const float* bk = (const float*)d_in[5];
  const float* Wv = (const float*)d_in[6];
  const float* bv = (const float*)d_in[7];
  const float* Wo = (const float*)d_in[8];
  const float* bo = (const float*)d_in[9];
  float* out = (float*)d_out;
  char* ws = (char*)d_ws;
  const size_t MB = 1 << 20;

  // workspace overlays (time-disjoint): total 44 MiB
  _Float16* Oph   = (_Float16*)(ws + 0);        // [0,16) MiB — written by attn (xh/wqkvT dead)
  _Float16* xh    = (_Float16*)(ws + 0);        // [0,8) MiB — live cvt->proj
  _Float16* wqkvT = (_Float16*)(ws + 8 * MB);   // [8,14) — live transpose->proj
  _Float16* woT   = (_Float16*)(ws + 16 * MB);  // [16,18) — live to end
  _Float16* Qh    = (_Float16*)(ws + 18 * MB);  // [18,26) — live proj->attn
  _Float16* ctxh  = (_Float16*)(ws + 18 * MB);  // [18,26) — written by merge (Qh dead)
  _Float16* Kh    = (_Float16*)(ws + 26 * MB);  // [26,34)
  _Float16* Vth   = (_Float16*)(ws + 34 * MB);  // [34,42)
  float*    mlw   = (float*)   (ws + 42 * MB);  // [42,44)

  k_cvt_x<<<dim3(4096), dim3(256), 0, stream>>>(x, xh);
  k_transpose_w<<<dim3(32, 32, 4), dim3(32, 8), 0, stream>>>(Wq, Wk, Wv, Wo, wqkvT, woT);
  k_gemm_proj<<<dim3(24, 32), dim3(256), 0, stream>>>(xh, wqkvT, bq, bk, bv, Qh, Kh, Vth);
  k_attn<<<dim3(16, 32, 2), dim3(256), 0, stream>>>(Qh, Kh, Vth, mask, Oph, mlw);
  k_merge<<<dim3(2048), dim3(256), 0, stream>>>(Oph, mlw, ctxh);
  k_gemm_out<<<dim3(8, 64), dim3(256), 0, stream>>>(ctxh, woT, bo, out);
}